// Round 3
// baseline (287.093 us; speedup 1.0000x reference)
//
#include <hip/hip_runtime.h>

// HadamardAdapter, fully analytic (H = Sylvester/64, orthogonal):
//   out[row,d] = x[row,d] + wloc[row][d&31] - wbar[d&31]
//   y[row][m]   = sum_{d&31==m} x[row,d]
//   cz[row][j]  = s_j * (1/64) sum_m y[row][m] (-1)^popc(j&m),  s_j = leaky(adapter_j)
//   wloc/wbar   = (1/64) * inverse 32-point transform of (cz - czbar)
// Single persistent kernel, hand-rolled grid barrier (1024 blocks, 4/CU
// guaranteed by __launch_bounds__(256,4): VGPR<=128, LDS ~3KB).

#define NROWS 8192
#define DDIM  4096
#define NK    24
#define NBLK  1024
#define RPB   8            // rows per block

typedef float v4f __attribute__((ext_vector_type(4)));

__global__ __launch_bounds__(256, 4) void hada_fused_persist(
    const float* __restrict__ x, const float* __restrict__ adapter,
    float* __restrict__ out, float* __restrict__ Y, unsigned* __restrict__ cnt)
{
    __shared__ __align__(16) float y[RPB][32];
    __shared__ float cz[RPB][NK];
    __shared__ float czb[NK];
    __shared__ __align__(16) float wsh[RPB][32];
    __shared__ float Ysh[32];

    const int t = threadIdx.x;
    const int wave = t >> 6, lane = t & 63;
    const int blk = blockIdx.x;

    // ---------- Phase 1: fold rows (one wave handles 2 rows) ----------
    for (int rr = 0; rr < 2; ++rr) {
        const int r = wave * 2 + rr;
        const size_t row = (size_t)blk * RPB + r;
        const v4f* __restrict__ xr = (const v4f*)x + row * (DDIM / 4);
        v4f acc = (v4f)0.f;
#pragma unroll
        for (int i = 0; i < 16; ++i) acc += xr[lane + 64 * i];
        // residue of lane's float4 = 4*(lane&7)+c (64*i*4 % 32 == 0)
#pragma unroll
        for (int off = 8; off < 64; off <<= 1) {
            acc.x += __shfl_xor(acc.x, off);
            acc.y += __shfl_xor(acc.y, off);
            acc.z += __shfl_xor(acc.z, off);
            acc.w += __shfl_xor(acc.w, off);
        }
        if (lane < 8) *(v4f*)&y[r][lane * 4] = acc;
    }
    __syncthreads();

    if (t < RPB * NK) {                       // per-row cz
        const int r = t / NK, j = t % NK;
        float zv = 0.f;
#pragma unroll
        for (int m = 0; m < 32; ++m)
            zv += (__popc(j & m) & 1) ? -y[r][m] : y[r][m];
        zv *= (1.f / 64.f);
        const float a = adapter[j];
        const float sc = (a > 0.f) ? a : 0.01f * a;   // leaky_relu
        cz[r][j] = sc * zv;
    }
    if (t >= 192 && t < 224) {                // block partial -> global Y
        const int m = t - 192;
        float s = 0.f;
#pragma unroll
        for (int r = 0; r < RPB; ++r) s += y[r][m];
        atomicAdd(&Y[m], s);
    }

    // ---------- Grid barrier ----------
    __threadfence();
    __syncthreads();
    if (t == 0) {
        atomicAdd(cnt, 1u);
        while (__hip_atomic_load(cnt, __ATOMIC_ACQUIRE, __HIP_MEMORY_SCOPE_AGENT) < NBLK)
            __builtin_amdgcn_s_sleep(2);
    }
    __syncthreads();

    // ---------- Phase 2: wbar (redundant per block), per-row w, apply ----------
    if (t < 32)
        Ysh[t] = __hip_atomic_load(&Y[t], __ATOMIC_RELAXED, __HIP_MEMORY_SCOPE_AGENT);
    __syncthreads();
    if (t < NK) {
        float zb = 0.f;
#pragma unroll
        for (int m = 0; m < 32; ++m)
            zb += (__popc(t & m) & 1) ? -Ysh[m] : Ysh[m];
        zb *= (1.f / 64.f) / (float)NROWS;
        const float a = adapter[t];
        const float sc = (a > 0.f) ? a : 0.01f * a;
        czb[t] = sc * zb;
    }
    __syncthreads();
    {
        const int r = t >> 5, m = t & 31;     // 256 threads = 8 rows x 32 m
        float wv = 0.f;
#pragma unroll
        for (int j = 0; j < NK; ++j) {
            const float c = cz[r][j] - czb[j];
            wv += (__popc(j & m) & 1) ? -c : c;
        }
        wsh[r][m] = wv * (1.f / 64.f);
    }
    __syncthreads();

    for (int rr = 0; rr < 2; ++rr) {
        const int r = wave * 2 + rr;
        const size_t row = (size_t)blk * RPB + r;
        const v4f* __restrict__ xr = (const v4f*)x + row * (DDIM / 4);
        v4f* __restrict__ orow = (v4f*)out + row * (DDIM / 4);
        const v4f w4 = *(const v4f*)&wsh[r][(lane & 7) * 4];
#pragma unroll
        for (int i = 0; i < 16; ++i)
            __builtin_nontemporal_store(xr[lane + 64 * i] + w4, &orow[lane + 64 * i]);
    }
}

extern "C" void kernel_launch(void* const* d_in, const int* in_sizes, int n_in,
                              void* d_out, int out_size, void* d_ws, size_t ws_size,
                              hipStream_t stream) {
    const float* x       = (const float*)d_in[0];   // (4,2048,4096) f32
    const float* adapter = (const float*)d_in[1];   // (24,) f32
    float* out = (float*)d_out;
    float* Y   = (float*)d_ws;                      // [32] global fold accumulator
    unsigned* cnt = (unsigned*)((char*)d_ws + 128); // barrier counter

    hipMemsetAsync(d_ws, 0, 256, stream);           // zero Y + cnt each call
    hipLaunchKernelGGL(hada_fused_persist, dim3(NBLK), dim3(256), 0, stream,
                       x, adapter, out, Y, cnt);
}

// Round 4
// 85.281 us; speedup vs baseline: 3.3665x; 3.3665x over previous
//
#include <hip/hip_runtime.h>

// HadamardAdapter, fully analytic (H = Sylvester/64, orthogonal):
//   out[row,d] = x[row,d] + wloc[row][d&31] - wbar[d&31]
// with y[row][m] = sum_{d&31==m} x[row,d],
//   cz[row][j]  = s_j*(1/64)*sum_m y[row][m]*(-1)^popc(j&m), s_j = leaky(adapter_j)
//   wloc[row][m] = (1/64)*sum_{j<24} cz[row][j]*(-1)^popc(j&m)
//   wbar from Y[m] = sum_rows y[row][m] (global fold; linear in x).
// Two kernels; the launch boundary is the device-scope barrier (round-3's
// in-kernel spin barrier caused an acquire/cache-invalidate storm: 4x regression).

#define NROWS 8192
#define DDIM  4096
#define NK    24
#define K1_BLOCKS 2048
#define K1_THREADS 256

typedef float v4f __attribute__((ext_vector_type(4)));

// ---------------- K1: global 32-residue fold -> Y[32] (device atomics) -------
__global__ __launch_bounds__(256) void hada_fold(const float* __restrict__ x,
                                                 float* __restrict__ Y)
{
    const int t = threadIdx.x;
    const int gtid = blockIdx.x * K1_THREADS + t;
    const v4f* __restrict__ xv = (const v4f*)x;
    v4f acc = (v4f)0.f;
    // 8388608 float4s; stride 2048*256 = 524288 (mult of 8 => residues fixed
    // per thread at m = 4*(t&7)+c); 16 iterations.
#pragma unroll
    for (int i = 0; i < 16; ++i)
        acc += xv[(size_t)i * (K1_BLOCKS * K1_THREADS) + gtid];

#pragma unroll
    for (int off = 8; off < 64; off <<= 1) {
        acc.x += __shfl_xor(acc.x, off);
        acc.y += __shfl_xor(acc.y, off);
        acc.z += __shfl_xor(acc.z, off);
        acc.w += __shfl_xor(acc.w, off);
    }
    __shared__ v4f yp[4][8];
    const int wave = t >> 6, lane = t & 63;
    if (lane < 8) yp[wave][lane] = acc;
    __syncthreads();
    if (t < 32) {
        float s = 0.f;
#pragma unroll
        for (int w = 0; w < 4; ++w) s += yp[w][t >> 2][t & 3];
        atomicAdd(&Y[t], s);   // 2048 adds per address, device scope: negligible
    }
}

// ---------------- K2: per-row wloc, redundant wbar, out = x + w --------------
__global__ __launch_bounds__(256) void hada_apply(const float* __restrict__ x,
                                                  const float* __restrict__ adapter,
                                                  const float* __restrict__ Y,
                                                  float* __restrict__ out)
{
    __shared__ v4f yp[4][8];
    __shared__ float y[32];
    __shared__ float cz[NK];
    __shared__ float czb[NK];
    __shared__ __align__(16) float wsh[32];
    const int t = threadIdx.x;
    const int wave = t >> 6, lane = t & 63;
    const size_t base = (size_t)blockIdx.x * (DDIM / 4);
    const v4f* __restrict__ xr = (const v4f*)x + base;

    v4f v0 = xr[t], v1 = xr[t + 256], v2 = xr[t + 512], v3 = xr[t + 768];
    v4f acc = (v0 + v1) + (v2 + v3);

#pragma unroll
    for (int off = 8; off < 64; off <<= 1) {
        acc.x += __shfl_xor(acc.x, off);
        acc.y += __shfl_xor(acc.y, off);
        acc.z += __shfl_xor(acc.z, off);
        acc.w += __shfl_xor(acc.w, off);
    }
    if (lane < 8) yp[wave][lane] = acc;
    __syncthreads();
    if (t < 32) {
        float s = 0.f;
#pragma unroll
        for (int w = 0; w < 4; ++w) s += yp[w][t >> 2][t & 3];
        y[t] = s;
    }
    __syncthreads();
    if (t < NK) {                        // per-row cz
        float zv = 0.f;
#pragma unroll
        for (int m = 0; m < 32; ++m)
            zv += (__popc(t & m) & 1) ? -y[m] : y[m];
        const float a = adapter[t];
        const float sc = (a > 0.f) ? a : 0.01f * a;     // leaky_relu slope 0.01
        cz[t] = sc * (zv * (1.f / 64.f));
    }
    if (t >= 64 && t < 64 + NK) {        // global czb (redundant per block, free)
        const int j = t - 64;
        float zb = 0.f;
#pragma unroll
        for (int m = 0; m < 32; ++m)
            zb += (__popc(j & m) & 1) ? -Y[m] : Y[m];
        zb *= (1.f / 64.f) / (float)NROWS;
        const float a = adapter[j];
        const float sc = (a > 0.f) ? a : 0.01f * a;
        czb[j] = sc * zb;
    }
    __syncthreads();
    if (t < 32) {
        float wv = 0.f;
#pragma unroll
        for (int j = 0; j < NK; ++j) {
            const float c = cz[j] - czb[j];
            wv += (__popc(j & t) & 1) ? -c : c;
        }
        wsh[t] = wv * (1.f / 64.f);
    }
    __syncthreads();

    const v4f w4 = *(const v4f*)&wsh[(t & 7) << 2];
    v4f* __restrict__ orow = (v4f*)out + base;
    __builtin_nontemporal_store(v0 + w4, &orow[t]);
    __builtin_nontemporal_store(v1 + w4, &orow[t + 256]);
    __builtin_nontemporal_store(v2 + w4, &orow[t + 512]);
    __builtin_nontemporal_store(v3 + w4, &orow[t + 768]);
}

extern "C" void kernel_launch(void* const* d_in, const int* in_sizes, int n_in,
                              void* d_out, int out_size, void* d_ws, size_t ws_size,
                              hipStream_t stream) {
    const float* x       = (const float*)d_in[0];   // (4,2048,4096) f32
    const float* adapter = (const float*)d_in[1];   // (24,) f32
    float* out = (float*)d_out;
    float* Y   = (float*)d_ws;                      // [32] global fold

    hipMemsetAsync(Y, 0, 32 * sizeof(float), stream);
    hipLaunchKernelGGL(hada_fold,  dim3(K1_BLOCKS), dim3(K1_THREADS), 0, stream, x, Y);
    hipLaunchKernelGGL(hada_apply, dim3(NROWS),     dim3(256),        0, stream,
                       x, adapter, Y, out);
}